// Round 6
// baseline (116.214 us; speedup 1.0000x reference)
//
#include <hip/hip_runtime.h>
#include <hip/hip_bf16.h>
#include <math.h>

#define DD 256
#define BB 8
#define TT 1024
#define MM (BB*TT)
#define NH 4
#define DKH 64
#define NQ 3

typedef __attribute__((ext_vector_type(8))) short bf16x8;
typedef __attribute__((ext_vector_type(4))) float f32x4;
typedef unsigned short u16;
typedef unsigned int u32;

__device__ __forceinline__ float bf2f(u16 u) {
  return __uint_as_float(((u32)u) << 16);
}
__device__ __forceinline__ u16 f2bf(float x) {
  __hip_bfloat16 h = __float2bfloat16(x);
  return *reinterpret_cast<u16*>(&h);
}
__device__ __forceinline__ uint2 pack4(float a, float b, float c, float d) {
  uint2 r;
  r.x = (u32)f2bf(a) | ((u32)f2bf(b) << 16);
  r.y = (u32)f2bf(c) | ((u32)f2bf(d) << 16);
  return r;
}
__device__ __forceinline__ float wred(float v) {
#pragma unroll
  for (int off = 32; off; off >>= 1) v += __shfl_xor(v, off);
  return v;
}

// ---------------------------------------------------------------------------
// Precast: 9 weight matrices (256x256 fp32) -> bf16 wb.
// order: [0]=g1_f1w [1]=g1_f2w [2]=g1_gw [3]=wk [4]=wv
//        [5]=wo_w [6]=g2_f1w [7]=g2_f2w [8]=g2_gw
// ---------------------------------------------------------------------------
#define NW8 (65536 / 8)
#define NCHUNK (9 * NW8)   // 73728

__global__ __launch_bounds__(256) void precast(
    const float* __restrict__ w0, const float* __restrict__ w1,
    const float* __restrict__ w2, const float* __restrict__ w3,
    const float* __restrict__ w4, const float* __restrict__ w5,
    const float* __restrict__ w6, const float* __restrict__ w7,
    const float* __restrict__ w8_, u16* __restrict__ wb)
{
  const int c = blockIdx.x * 256 + threadIdx.x;
  if (c >= NCHUNK) return;
  const int mi = c / NW8;
  const int off = (c - mi * NW8) * 8;
  const float* src;
  switch (mi) {
    case 0: src = w0; break; case 1: src = w1; break;
    case 2: src = w2; break; case 3: src = w3; break;
    case 4: src = w4; break; case 5: src = w5; break;
    case 6: src = w6; break; case 7: src = w7; break;
    default: src = w8_; break;
  }
  u16* dst = wb + mi * 65536;
  const float4 v0 = *(const float4*)(src + off);
  const float4 v1 = *(const float4*)(src + off + 4);
  *(uint2*)(dst + off)     = pack4(v0.x, v0.y, v0.z, v0.w);
  *(uint2*)(dst + off + 4) = pack4(v1.x, v1.y, v1.z, v1.w);
}

// ---------------------------------------------------------------------------
// MEGA: per block (64 rows): eta1=ELU(x@f1w^T+b) -> eta2=eta1@f2w^T+b ->
// h=LN(x+sigmoid(eta2@gw^T+gb)*eta2) -> K=h@wk^T, V=h@wv^T.
// Weight chunks (64 out-rows x 256 K, bf16) stream through Ws with
// register-staged double buffering (loads for chunk w+2 in flight during
// compute of w+1). Intermediates live in LDS only.
// ---------------------------------------------------------------------------
__global__ __launch_bounds__(256) void mega(
    const float* __restrict__ x, const u16* __restrict__ wb,
    const float* __restrict__ f1b, const float* __restrict__ f2b,
    const float* __restrict__ gb, const float* __restrict__ lng,
    const float* __restrict__ lnb,
    u16* __restrict__ kout, u16* __restrict__ vout,
    float* __restrict__ hlast)
{
  __shared__ u16 bufA[64][264];   // x -> eta2
  __shared__ u16 bufB[64][264];   // eta1 -> pre -> h
  __shared__ u16 Ws[64][264];     // current weight chunk
  __shared__ float red_s[64][2];
  __shared__ float red_q[64][2];
  __shared__ float smean[64], srstd[64];

  const int tid  = threadIdx.x;
  const int lane = tid & 63, wave = tid >> 6;
  const int wr = wave >> 1, wc = wave & 1;
  const int q  = lane >> 4, lr = lane & 15;
  const int r0 = blockIdx.x * 64;

  uint4 wreg[8];

#define LOADW(w_) { \
  const u16* wp_ = wb + (size_t)((w_) >> 2) * 65536 + ((w_) & 3) * 16384; \
  _Pragma("unroll") \
  for (int p = 0; p < 8; ++p) wreg[p] = *(const uint4*)(wp_ + (p * 256 + tid) * 8); }

#define STOREW() { \
  _Pragma("unroll") \
  for (int p = 0; p < 8; ++p) { \
    const int e_ = (p * 256 + tid) * 8; \
    *(uint4*)&Ws[e_ >> 8][e_ & 255] = wreg[p]; } }

#define ADVANCE() { __syncthreads(); STOREW(); if (w + 2 < 20) LOADW(w + 2); __syncthreads(); }

#define MFMA_CHUNK(ABUF) \
  _Pragma("unroll") \
  for (int kk = 0; kk < 8; ++kk) { \
    const int koff = kk * 32 + q * 8; \
    const bf16x8 a0 = *(const bf16x8*)&ABUF[wr * 32 + lr][koff]; \
    const bf16x8 a1 = *(const bf16x8*)&ABUF[wr * 32 + 16 + lr][koff]; \
    const bf16x8 b0 = *(const bf16x8*)&Ws[wc * 32 + lr][koff]; \
    const bf16x8 b1 = *(const bf16x8*)&Ws[wc * 32 + 16 + lr][koff]; \
    acc[0][0] = __builtin_amdgcn_mfma_f32_16x16x32_bf16(a0, b0, acc[0][0], 0, 0, 0); \
    acc[0][1] = __builtin_amdgcn_mfma_f32_16x16x32_bf16(a0, b1, acc[0][1], 0, 0, 0); \
    acc[1][0] = __builtin_amdgcn_mfma_f32_16x16x32_bf16(a1, b0, acc[1][0], 0, 0, 0); \
    acc[1][1] = __builtin_amdgcn_mfma_f32_16x16x32_bf16(a1, b1, acc[1][1], 0, 0, 0); \
  }

  // ---- prologue: W chunk 0 + x staging (fp32 -> bf16)
  LOADW(0);
#pragma unroll
  for (int p = 0; p < 8; ++p) {
    const int e = (p * 256 + tid) * 8;
    const int row = e >> 8, col = e & 255;
    const float* xp = x + (size_t)(r0 + row) * DD + col;
    const float4 v0 = *(const float4*)xp;
    const float4 v1 = *(const float4*)(xp + 4);
    *(uint2*)&bufA[row][col]     = pack4(v0.x, v0.y, v0.z, v0.w);
    *(uint2*)&bufA[row][col + 4] = pack4(v1.x, v1.y, v1.z, v1.w);
  }
  __syncthreads();
  STOREW();
  LOADW(1);
  __syncthreads();

  int w = 0;
  float rs[2][4] = {{0}}, rq[2][4] = {{0}};

  // ---------------- stage 1: eta1 = ELU(x @ f1w^T + f1b) -> bufB
  for (int nc = 0; nc < 4; ++nc, ++w) {
    f32x4 acc[2][2] = {};
    MFMA_CHUNK(bufA);
#pragma unroll
    for (int i = 0; i < 2; ++i)
#pragma unroll
      for (int j = 0; j < 2; ++j) {
        const int col = nc * 64 + wc * 32 + j * 16 + lr;
        const float bias = f1b[col];
#pragma unroll
        for (int t = 0; t < 4; ++t) {
          const int row = wr * 32 + i * 16 + q * 4 + t;
          float v = acc[i][j][t] + bias;
          v = v > 0.f ? v : expm1f(v);
          bufB[row][col] = f2bf(v);
        }
      }
    ADVANCE();
  }

  // ---------------- stage 2: eta2 = eta1 @ f2w^T + f2b -> bufA
  for (int nc = 0; nc < 4; ++nc, ++w) {
    f32x4 acc[2][2] = {};
    MFMA_CHUNK(bufB);
#pragma unroll
    for (int i = 0; i < 2; ++i)
#pragma unroll
      for (int j = 0; j < 2; ++j) {
        const int col = nc * 64 + wc * 32 + j * 16 + lr;
        const float bias = f2b[col];
#pragma unroll
        for (int t = 0; t < 4; ++t) {
          const int row = wr * 32 + i * 16 + q * 4 + t;
          bufA[row][col] = f2bf(acc[i][j][t] + bias);
        }
      }
    ADVANCE();
  }

  // ---------------- stage 3: gate -> sigmoid -> pre = x + sig*eta2 -> bufB
  for (int nc = 0; nc < 4; ++nc, ++w) {
    float xr[2][2][4];
#pragma unroll
    for (int i = 0; i < 2; ++i)
#pragma unroll
      for (int j = 0; j < 2; ++j) {
        const int col = nc * 64 + wc * 32 + j * 16 + lr;
#pragma unroll
        for (int t = 0; t < 4; ++t)
          xr[i][j][t] = x[(size_t)(r0 + wr * 32 + i * 16 + q * 4 + t) * DD + col];
      }
    f32x4 acc[2][2] = {};
    MFMA_CHUNK(bufA);
#pragma unroll
    for (int i = 0; i < 2; ++i)
#pragma unroll
      for (int j = 0; j < 2; ++j) {
        const int col = nc * 64 + wc * 32 + j * 16 + lr;
        const float gbn = gb[col];
#pragma unroll
        for (int t = 0; t < 4; ++t) {
          const int row = wr * 32 + i * 16 + q * 4 + t;
          const float gate = acc[i][j][t] + gbn;
          const float sig = 1.f / (1.f + expf(-gate));
          const float e2 = bf2f(bufA[row][col]);
          const float pre = xr[i][j][t] + sig * e2;
          rs[i][t] += pre;
          rq[i][t] += pre * pre;
          bufB[row][col] = f2bf(pre);
        }
      }
    ADVANCE();
  }

  // ---------------- LayerNorm over bufB rows -> h (in place)
#pragma unroll
  for (int i = 0; i < 2; ++i)
#pragma unroll
    for (int t = 0; t < 4; ++t) {
      float s = rs[i][t], sq = rq[i][t];
#pragma unroll
      for (int m = 1; m <= 8; m <<= 1) { s += __shfl_xor(s, m); sq += __shfl_xor(sq, m); }
      if (lr == 0) {
        const int row = wr * 32 + i * 16 + q * 4 + t;
        red_s[row][wc] = s;
        red_q[row][wc] = sq;
      }
    }
  __syncthreads();
  if (tid < 64) {
    const float s  = red_s[tid][0] + red_s[tid][1];
    const float sq = red_q[tid][0] + red_q[tid][1];
    const float mean = s * (1.f / DD);
    smean[tid] = mean;
    srstd[tid] = rsqrtf(sq * (1.f / DD) - mean * mean + 1e-5f);
  }
  __syncthreads();
  const bool lastblk = ((r0 + 63) & (TT - 1)) == (TT - 1);
#pragma unroll
  for (int nc = 0; nc < 4; ++nc)
#pragma unroll
    for (int i = 0; i < 2; ++i)
#pragma unroll
      for (int j = 0; j < 2; ++j) {
        const int col = nc * 64 + wc * 32 + j * 16 + lr;
        const float gn = lng[col], bn = lnb[col];
#pragma unroll
        for (int t = 0; t < 4; ++t) {
          const int row = wr * 32 + i * 16 + q * 4 + t;
          const float h = (bf2f(bufB[row][col]) - smean[row]) * srstd[row] * gn + bn;
          bufB[row][col] = f2bf(h);
          if (lastblk && row == 63)
            hlast[(size_t)(r0 >> 10) * DD + col] = h;
        }
      }
  __syncthreads();

  // ---------------- stage 4: K = h @ wk^T -> global
  for (int nc = 0; nc < 4; ++nc, ++w) {
    f32x4 acc[2][2] = {};
    MFMA_CHUNK(bufB);
#pragma unroll
    for (int i = 0; i < 2; ++i)
#pragma unroll
      for (int j = 0; j < 2; ++j) {
        const int col = nc * 64 + wc * 32 + j * 16 + lr;
#pragma unroll
        for (int t = 0; t < 4; ++t) {
          const int row = wr * 32 + i * 16 + q * 4 + t;
          kout[(size_t)(r0 + row) * DD + col] = f2bf(acc[i][j][t]);
        }
      }
    ADVANCE();
  }

  // ---------------- stage 5: V = h @ wv^T -> global
  for (int nc = 0; nc < 4; ++nc, ++w) {
    f32x4 acc[2][2] = {};
    MFMA_CHUNK(bufB);
#pragma unroll
    for (int i = 0; i < 2; ++i)
#pragma unroll
      for (int j = 0; j < 2; ++j) {
        const int col = nc * 64 + wc * 32 + j * 16 + lr;
#pragma unroll
        for (int t = 0; t < 4; ++t) {
          const int row = wr * 32 + i * 16 + q * 4 + t;
          vout[(size_t)(r0 + row) * DD + col] = f2bf(acc[i][j][t]);
        }
      }
    if (w < 19) ADVANCE();
  }
#undef LOADW
#undef STOREW
#undef ADVANCE
#undef MFMA_CHUNK
}

// ---------------------------------------------------------------------------
// Attention: q, scores, softmax, per-head ctx. grid (NH, BB).
// ---------------------------------------------------------------------------
__global__ __launch_bounds__(256) void qk_softmax_ctx(
    const float* __restrict__ hlast, const u16* __restrict__ kbuf,
    const u16* __restrict__ vbuf, const float* __restrict__ wq,
    float* __restrict__ ctxbuf)
{
  __shared__ float hl[DD], qh[DKH];
  __shared__ float red[8];
  __shared__ float pr[TT];
  __shared__ float part[8][DKH];
  const int h = blockIdx.x, b = blockIdx.y;
  const int tid = threadIdx.x, lane = tid & 63, w = tid >> 6;

  hl[tid] = hlast[(size_t)b * DD + tid];
  __syncthreads();
  {
    const int j = tid >> 2, seg = tid & 3;
    const float* wr = wq + (size_t)(h * DKH + j) * DD + seg * 64;
    const float* sp = hl + seg * 64;
    float acc = 0.f;
#pragma unroll
    for (int k = 0; k < 64; k += 4) {
      const float4 w4 = *(const float4*)(wr + k);
      acc += w4.x * sp[k] + w4.y * sp[k + 1] + w4.z * sp[k + 2] + w4.w * sp[k + 3];
    }
    acc += __shfl_xor(acc, 1);
    acc += __shfl_xor(acc, 2);
    if (seg == 0) qh[j] = acc;
  }
  __syncthreads();

  float sv[4], mx = -3.0e38f;
#pragma unroll
  for (int i = 0; i < 4; ++i) {
    const int s = tid + 256 * i;
    const u16* kr = kbuf + ((size_t)(b * TT + s)) * DD + h * DKH;
    float acc = 0.f;
#pragma unroll
    for (int d = 0; d < DKH; d += 8) {
      const bf16x8 kv = *(const bf16x8*)(kr + d);
#pragma unroll
      for (int e = 0; e < 8; ++e) acc += bf2f((u16)kv[e]) * qh[d + e];
    }
    sv[i] = acc * 0.125f;
    mx = fmaxf(mx, sv[i]);
  }
#pragma unroll
  for (int off = 32; off; off >>= 1) mx = fmaxf(mx, __shfl_xor(mx, off));
  if (lane == 0) red[w] = mx;
  __syncthreads();
  mx = fmaxf(fmaxf(red[0], red[1]), fmaxf(red[2], red[3]));
  float sum = 0.f;
#pragma unroll
  for (int i = 0; i < 4; ++i) { sv[i] = expf(sv[i] - mx); sum += sv[i]; }
  sum = wred(sum);
  if (lane == 0) red[4 + w] = sum;
  __syncthreads();
  const float inv = 1.f / (red[4] + red[5] + red[6] + red[7]);
#pragma unroll
  for (int i = 0; i < 4; ++i) pr[tid + 256 * i] = sv[i] * inv;
  __syncthreads();

  {
    const int np = (tid & 31) * 2, sg = tid >> 5;
    const u16* vp = vbuf + ((size_t)(b * TT + sg * 128)) * DD + h * DKH + np;
    const float* pp = pr + sg * 128;
    float a0 = 0.f, a1 = 0.f;
    for (int s = 0; s < 128; ++s) {
      const u32 vv = *(const u32*)(vp + (size_t)s * DD);
      const float p = pp[s];
      a0 += p * bf2f((u16)(vv & 0xffffu));
      a1 += p * bf2f((u16)(vv >> 16));
    }
    part[sg][np] = a0; part[sg][np + 1] = a1;
  }
  __syncthreads();
  if (tid < DKH) {
    float s = 0.f;
#pragma unroll
    for (int g = 0; g < 8; ++g) s += part[g][tid];
    ctxbuf[(size_t)b * DD + h * DKH + tid] = s;
  }
}

// ---------------------------------------------------------------------------
// Coalesced matvec: 16 waves x 16 rows; 32-lane halves own a row each iter.
// ---------------------------------------------------------------------------
__device__ __forceinline__ void mv256b(const u16* __restrict__ W16,
                                       const float* __restrict__ srcbuf,
                                       float* __restrict__ dst,
                                       int wave, int lane)
{
  const int half = lane >> 5, l32 = lane & 31;
  float s[8];
  {
    const float4 s0 = *(const float4*)(srcbuf + l32 * 8);
    const float4 s1 = *(const float4*)(srcbuf + l32 * 8 + 4);
    s[0] = s0.x; s[1] = s0.y; s[2] = s0.z; s[3] = s0.w;
    s[4] = s1.x; s[5] = s1.y; s[6] = s1.z; s[7] = s1.w;
  }
#pragma unroll
  for (int i = 0; i < 8; ++i) {
    const int r = wave * 16 + i * 2 + half;
    const bf16x8 wv = *(const bf16x8*)(W16 + (size_t)r * DD + l32 * 8);
    float acc = 0.f;
#pragma unroll
    for (int e = 0; e < 8; ++e) acc += bf2f((u16)wv[e]) * s[e];
#pragma unroll
    for (int off = 16; off; off >>= 1) acc += __shfl_xor(acc, off);
    if (l32 == 0) dst[r] = acc;
  }
}

#define LN_STEP(val, gam, bet, dst) \
  __syncthreads(); \
  if (tid < DD) { lnS[tid] = (val); lnQ[tid] = (val) * (val); } \
  __syncthreads(); \
  if (tid < 64) { \
    float s_ = 0.f, q_ = 0.f; \
    _Pragma("unroll") \
    for (int i_ = 0; i_ < 4; ++i_) { s_ += lnS[tid + 64 * i_]; q_ += lnQ[tid + 64 * i_]; } \
    s_ = wred(s_); q_ = wred(q_); \
    if (tid == 0) { const float m_ = s_ * (1.f / DD); red2[0] = m_; red2[1] = rsqrtf(q_ * (1.f / DD) - m_ * m_ + 1e-5f); } \
  } \
  __syncthreads(); \
  if (tid < DD) dst[tid] = ((val) - red2[0]) * red2[1] * gam[tid] + bet[tid]; \
  __syncthreads();

// ---------------------------------------------------------------------------
// Tail: out-proj + LN + GRN2 + quantile head. grid(BB), 1024 threads.
// ---------------------------------------------------------------------------
__global__ __launch_bounds__(1024) void tail2(
    const float* __restrict__ hlast, const float* __restrict__ ctxbuf,
    const u16* __restrict__ wbf,
    const float* __restrict__ wob, const float* __restrict__ alng, const float* __restrict__ alnb,
    const float* __restrict__ f1b, const float* __restrict__ f2b,
    const float* __restrict__ gbv, const float* __restrict__ lng, const float* __restrict__ lnb,
    const float* __restrict__ qhw, const float* __restrict__ qhb,
    float* __restrict__ out)
{
  __shared__ float hl[DD], bufA[DD], bufB[DD], bufC[DD], part0[DD];
  __shared__ float lnS[DD], lnQ[DD];
  __shared__ float red2[2];
  const int b = blockIdx.x, tid = threadIdx.x;
  const int wave = tid >> 6, lane = tid & 63;

  if (tid < DD) {
    hl[tid]   = hlast[(size_t)b * DD + tid];
    bufB[tid] = ctxbuf[(size_t)b * DD + tid];
  }
  __syncthreads();

  mv256b(wbf + 0 * 65536, bufB, part0, wave, lane);
  __syncthreads();
  float v = 0.f;
  if (tid < DD) v = hl[tid] + part0[tid] + wob[tid];
  LN_STEP(v, alng, alnb, bufA)

  mv256b(wbf + 1 * 65536, bufA, part0, wave, lane);
  __syncthreads();
  if (tid < DD) {
    const float e1 = part0[tid] + f1b[tid];
    bufB[tid] = e1 > 0.f ? e1 : expm1f(e1);
  }
  __syncthreads();

  mv256b(wbf + 2 * 65536, bufB, part0, wave, lane);
  __syncthreads();
  if (tid < DD) bufC[tid] = part0[tid] + f2b[tid];
  __syncthreads();

  mv256b(wbf + 3 * 65536, bufC, part0, wave, lane);
  __syncthreads();
  v = 0.f;
  if (tid < DD) {
    const float g = part0[tid] + gbv[tid];
    v = bufA[tid] + (1.f / (1.f + expf(-g))) * bufC[tid];
  }
  LN_STEP(v, lng, lnb, bufA)

  if (tid < 64 * NQ) {
    const int qi = tid >> 6, l = tid & 63;
    float acc = 0.f;
#pragma unroll
    for (int i = 0; i < 4; ++i) acc += qhw[(size_t)qi * DD + l + 64 * i] * bufA[l + 64 * i];
    acc = wred(acc);
    if (l == 0) out[b * NQ + qi] = acc + qhb[qi];
  }
}

// ---------------------------------------------------------------------------
extern "C" void kernel_launch(void* const* d_in, const int* in_sizes, int n_in,
                              void* d_out, int out_size, void* d_ws, size_t ws_size,
                              hipStream_t stream)
{
  const float* x       = (const float*)d_in[0];
  const float* g1_f1w  = (const float*)d_in[1];
  const float* g1_f1b  = (const float*)d_in[2];
  const float* g1_f2w  = (const float*)d_in[3];
  const float* g1_f2b  = (const float*)d_in[4];
  const float* g1_gw   = (const float*)d_in[5];
  const float* g1_gb   = (const float*)d_in[6];
  const float* g1_lng  = (const float*)d_in[7];
  const float* g1_lnb  = (const float*)d_in[8];
  const float* wq      = (const float*)d_in[9];
  const float* wk      = (const float*)d_in[10];
  const float* wv      = (const float*)d_in[11];
  const float* wo_w    = (const float*)d_in[12];
  const float* wo_b    = (const float*)d_in[13];
  const float* attn_lng= (const float*)d_in[14];
  const float* attn_lnb= (const float*)d_in[15];
  const float* g2_f1w  = (const float*)d_in[16];
  const float* g2_f1b  = (const float*)d_in[17];
  const float* g2_f2w  = (const float*)d_in[18];
  const float* g2_f2b  = (const float*)d_in[19];
  const float* g2_gw   = (const float*)d_in[20];
  const float* g2_gb   = (const float*)d_in[21];
  const float* g2_lng  = (const float*)d_in[22];
  const float* g2_lnb  = (const float*)d_in[23];
  const float* qh_w    = (const float*)d_in[24];
  const float* qh_b    = (const float*)d_in[25];
  float* out = (float*)d_out;

  char* w8 = (char*)d_ws;
  u16*  wb    = (u16*)(w8);                           // 9 * 128 KB bf16 weights
  u16*  kbuf  = (u16*)(w8 + ((size_t)2  << 20));      // 4 MB
  u16*  vbuf  = (u16*)(w8 + ((size_t)6  << 20));      // 4 MB
  float* hlast  = (float*)(w8 + ((size_t)10 << 20));  // 8 KB
  float* ctxbuf = (float*)(w8 + ((size_t)10 << 20) + (64 << 10));

  const dim3 blk(256);

  precast<<<dim3((NCHUNK + 255) / 256), blk, 0, stream>>>(
      g1_f1w, g1_f2w, g1_gw, wk, wv, wo_w, g2_f1w, g2_f2w, g2_gw, wb);
  mega<<<dim3(MM / 64), blk, 0, stream>>>(x, wb, g1_f1b, g1_f2b, g1_gb,
                                          g1_lng, g1_lnb, kbuf, vbuf, hlast);
  qk_softmax_ctx<<<dim3(NH, BB), blk, 0, stream>>>(hlast, kbuf, vbuf, wq, ctxbuf);
  tail2<<<dim3(BB), dim3(1024), 0, stream>>>(hlast, ctxbuf, wb + 5 * 65536,
                                             wo_b, attn_lng, attn_lnb,
                                             g2_f1b, g2_f2b, g2_gb, g2_lng, g2_lnb,
                                             qh_w, qh_b, out);
}

// Round 7
// 89.602 us; speedup vs baseline: 1.2970x; 1.2970x over previous
//
#include <hip/hip_runtime.h>
#include <hip/hip_bf16.h>
#include <math.h>

#define DD 256
#define BB 8
#define TT 1024
#define MM (BB*TT)
#define NH 4
#define DKH 64
#define NQ 3
#define SPLIT 16
#define SROWS (TT/SPLIT)   // 64

typedef __attribute__((ext_vector_type(8))) short bf16x8;
typedef __attribute__((ext_vector_type(4))) float f32x4;
typedef unsigned short u16;
typedef unsigned int u32;

__device__ __forceinline__ float bf2f(u16 u) {
  return __uint_as_float(((u32)u) << 16);
}
__device__ __forceinline__ u16 f2bf(float x) {
  __hip_bfloat16 h = __float2bfloat16(x);
  return *reinterpret_cast<u16*>(&h);
}
__device__ __forceinline__ uint2 pack4(float a, float b, float c, float d) {
  uint2 r;
  r.x = (u32)f2bf(a) | ((u32)f2bf(b) << 16);
  r.y = (u32)f2bf(c) | ((u32)f2bf(d) << 16);
  return r;
}
__device__ __forceinline__ float wred(float v) {
#pragma unroll
  for (int off = 32; off; off >>= 1) v += __shfl_xor(v, off);
  return v;
}

// ---------------------------------------------------------------------------
// Single-stage GEMM: out[M,256] = act(A[M,256] @ W[256,256]^T + bias).
// Full K staged once (one barrier). W fp32 (cvt in staging, proven free).
// ---------------------------------------------------------------------------
template<bool ABF, int ACT>   // ACT: 0 = none, 1 = ELU
__global__ __launch_bounds__(256) void gemm64(const void* __restrict__ A_,
                                              const float* __restrict__ W,
                                              const float* __restrict__ bias,
                                              u16* __restrict__ out)
{
  __shared__ u16 As[64][264];
  __shared__ u16 Bs[64][264];
  const int tid  = threadIdx.x;
  const int lane = tid & 63, wave = tid >> 6;
  const int wr = wave >> 1, wc = wave & 1;
  const int q  = lane >> 4, lr = lane & 15;
  const int m0 = blockIdx.x * 64, n0 = blockIdx.y * 64;

#pragma unroll
  for (int p = 0; p < 8; ++p) {
    const int c = tid + p * 256;
    const int row = c >> 5, col = (c & 31) * 8;
    if constexpr (ABF) {
      *(uint4*)&As[row][col] = *(const uint4*)((const u16*)A_ + (size_t)(m0 + row) * DD + col);
    } else {
      const float* ap = (const float*)A_ + (size_t)(m0 + row) * DD + col;
      const float4 v0 = *(const float4*)ap, v1 = *(const float4*)(ap + 4);
      *(uint2*)&As[row][col]     = pack4(v0.x, v0.y, v0.z, v0.w);
      *(uint2*)&As[row][col + 4] = pack4(v1.x, v1.y, v1.z, v1.w);
    }
    const float* wp = W + (size_t)(n0 + row) * DD + col;
    const float4 w0 = *(const float4*)wp, w1 = *(const float4*)(wp + 4);
    *(uint2*)&Bs[row][col]     = pack4(w0.x, w0.y, w0.z, w0.w);
    *(uint2*)&Bs[row][col + 4] = pack4(w1.x, w1.y, w1.z, w1.w);
  }
  __syncthreads();

  f32x4 acc[2][2] = {};
#pragma unroll
  for (int kk = 0; kk < 8; ++kk) {
    const int koff = kk * 32 + q * 8;
    bf16x8 av[2], bv[2];
    av[0] = *(const bf16x8*)&As[wr * 32 + lr][koff];
    av[1] = *(const bf16x8*)&As[wr * 32 + 16 + lr][koff];
    bv[0] = *(const bf16x8*)&Bs[wc * 32 + lr][koff];
    bv[1] = *(const bf16x8*)&Bs[wc * 32 + 16 + lr][koff];
#pragma unroll
    for (int i = 0; i < 2; ++i)
#pragma unroll
      for (int j = 0; j < 2; ++j)
        acc[i][j] = __builtin_amdgcn_mfma_f32_16x16x32_bf16(av[i], bv[j], acc[i][j], 0, 0, 0);
  }

#pragma unroll
  for (int i = 0; i < 2; ++i) {
#pragma unroll
    for (int j = 0; j < 2; ++j) {
      const int col = n0 + wc * 32 + j * 16 + lr;
      const float bvv = bias ? bias[col] : 0.f;
#pragma unroll
      for (int t = 0; t < 4; ++t) {
        const int row = m0 + wr * 32 + i * 16 + q * 4 + t;
        float v = acc[i][j][t] + bvv;
        if (ACT == 1) v = v > 0.f ? v : expm1f(v);
        out[(size_t)row * DD + col] = f2bf(v);
      }
    }
  }
}

// ---------------------------------------------------------------------------
// K3: gate = eta2 @ gw^T + gb; h = LN(x + sigmoid(gate)*eta2) fused.
// ---------------------------------------------------------------------------
__global__ __launch_bounds__(256) void grn_gate_ln(
    const u16* __restrict__ eta2, const float* __restrict__ W,
    const float* __restrict__ gb, const float* __restrict__ x,
    const float* __restrict__ lng, const float* __restrict__ lnb,
    u16* __restrict__ hout, float* __restrict__ hlast)
{
  __shared__ u16 As[32][136];
  __shared__ u16 Bs[256][136];
  __shared__ float red_s[32][5];
  __shared__ float red_q[32][5];
  __shared__ float smean[32], srstd[32];

  const int tid  = threadIdx.x;
  const int lane = tid & 63, wave = tid >> 6;
  const int q  = lane >> 4, lr = lane & 15;
  const int m0 = blockIdx.x * 32;

  f32x4 acc[2][4] = {};

  for (int k0 = 0; k0 < DD; k0 += 128) {
#pragma unroll
    for (int p = 0; p < 2; ++p) {
      const int c = tid + p * 256;
      const int row = c >> 4, col = (c & 15) * 8;
      *(uint4*)&As[row][col] = *(const uint4*)(eta2 + (size_t)(m0 + row) * DD + k0 + col);
    }
#pragma unroll
    for (int p = 0; p < 16; ++p) {
      const int c = tid + p * 256;
      const int row = c >> 4, col = (c & 15) * 8;
      const float* wp = W + (size_t)row * DD + k0 + col;
      const float4 w0 = *(const float4*)wp, w1 = *(const float4*)(wp + 4);
      *(uint2*)&Bs[row][col]     = pack4(w0.x, w0.y, w0.z, w0.w);
      *(uint2*)&Bs[row][col + 4] = pack4(w1.x, w1.y, w1.z, w1.w);
    }
    __syncthreads();
#pragma unroll
    for (int kk = 0; kk < 4; ++kk) {
      const int koff = kk * 32 + q * 8;
      bf16x8 av[2], bv[4];
#pragma unroll
      for (int i = 0; i < 2; ++i) av[i] = *(const bf16x8*)&As[i * 16 + lr][koff];
#pragma unroll
      for (int j = 0; j < 4; ++j) bv[j] = *(const bf16x8*)&Bs[wave * 64 + j * 16 + lr][koff];
#pragma unroll
      for (int i = 0; i < 2; ++i)
#pragma unroll
        for (int j = 0; j < 4; ++j)
          acc[i][j] = __builtin_amdgcn_mfma_f32_16x16x32_bf16(av[i], bv[j], acc[i][j], 0, 0, 0);
    }
    __syncthreads();
  }

  float pre[2][4][4];
#pragma unroll
  for (int i = 0; i < 2; ++i) {
#pragma unroll
    for (int j = 0; j < 4; ++j) {
      const int n = wave * 64 + j * 16 + lr;
      const float gbn = gb[n];
#pragma unroll
      for (int t = 0; t < 4; ++t) {
        const int grow = m0 + i * 16 + q * 4 + t;
        const float gate = acc[i][j][t] + gbn;
        const float sig = 1.f / (1.f + expf(-gate));
        const float e2 = bf2f(eta2[(size_t)grow * DD + n]);
        pre[i][j][t] = x[(size_t)grow * DD + n] + sig * e2;
      }
    }
  }
#pragma unroll
  for (int i = 0; i < 2; ++i) {
#pragma unroll
    for (int t = 0; t < 4; ++t) {
      float s = 0.f, sq = 0.f;
#pragma unroll
      for (int j = 0; j < 4; ++j) { const float v = pre[i][j][t]; s += v; sq += v * v; }
#pragma unroll
      for (int m = 1; m <= 8; m <<= 1) { s += __shfl_xor(s, m); sq += __shfl_xor(sq, m); }
      if (lr == 0) {
        const int ml = i * 16 + q * 4 + t;
        red_s[ml][wave] = s;
        red_q[ml][wave] = sq;
      }
    }
  }
  __syncthreads();
  if (tid < 32) {
    const float s  = red_s[tid][0] + red_s[tid][1] + red_s[tid][2] + red_s[tid][3];
    const float sq = red_q[tid][0] + red_q[tid][1] + red_q[tid][2] + red_q[tid][3];
    const float mean = s * (1.f / DD);
    const float var = sq * (1.f / DD) - mean * mean;
    smean[tid] = mean;
    srstd[tid] = rsqrtf(var + 1e-5f);
  }
  __syncthreads();
#pragma unroll
  for (int i = 0; i < 2; ++i) {
#pragma unroll
    for (int j = 0; j < 4; ++j) {
      const int n = wave * 64 + j * 16 + lr;
      const float gn = lng[n], bn = lnb[n];
#pragma unroll
      for (int t = 0; t < 4; ++t) {
        const int ml = i * 16 + q * 4 + t;
        const int grow = m0 + ml;
        const float hn = (pre[i][j][t] - smean[ml]) * srstd[ml] * gn + bn;
        hout[(size_t)grow * DD + n] = f2bf(hn);
        if ((grow & (TT - 1)) == (TT - 1))
          hlast[(size_t)(grow >> 10) * DD + n] = hn;
      }
    }
  }
}

// ---------------------------------------------------------------------------
// attn_partial: K/V-free attention. grid (SPLIT, BB), 256 threads.
// Per block: qk_vec = (hlast@wq^T)@wk (per head, scale folded), then stream
// 64 rows of h: E = exp(h·qk_vec) (max-free, clamped), accumulate
// den = sum E, eh = sum E*h. Writes per-chunk partials. Also casts the 5
// tail weight matrices to bf16 (wo,f1,f2,gw,wv), spread over 128 blocks.
// ---------------------------------------------------------------------------
__global__ __launch_bounds__(256) void attn_partial(
    const float* __restrict__ hlast, const u16* __restrict__ hbuf,
    const float* __restrict__ wq, const float* __restrict__ wk,
    const float* __restrict__ wo_w, const float* __restrict__ f1w,
    const float* __restrict__ f2w, const float* __restrict__ gw,
    const float* __restrict__ wv,
    u16* __restrict__ wbf,
    float* __restrict__ p_eh,   // [BB][SPLIT][NH][DD]
    float* __restrict__ p_den)  // [BB][SPLIT][NH]
{
  __shared__ float hl[DD];
  __shared__ float qv[DD];
  __shared__ float qk[NH][DD];
  __shared__ float ehp[4][NH][DD];
  __shared__ float denp[4][NH];
  const int chunk = blockIdx.x, b = blockIdx.y;
  const int tid = threadIdx.x, lane = tid & 63, w = tid >> 6;
  const int l32 = lane & 31, half = lane >> 5;

  // ---- tail-weight cast: 5 matrices * 65536 / 128 blocks = 2560 elems
  {
    const int bid = b * SPLIT + chunk;
    const int base = bid * 2560;
#pragma unroll
    for (int r = 0; r < 10; ++r) {
      const int e = base + r * 256 + tid;
      const int mi = e >> 16, off = e & 65535;
      const float* s = (mi == 0) ? wo_w : (mi == 1) ? f1w : (mi == 2) ? f2w
                     : (mi == 3) ? gw : wv;
      wbf[e] = f2bf(s[off]);
    }
  }

  if (tid < DD) hl[tid] = hlast[(size_t)b * DD + tid];
  __syncthreads();

  // ---- q = hlast @ wq^T (256 outs), coalesced wave-per-row
  {
    float sv[8];
    const float4 s0 = *(const float4*)(hl + l32 * 8);
    const float4 s1 = *(const float4*)(hl + l32 * 8 + 4);
    sv[0] = s0.x; sv[1] = s0.y; sv[2] = s0.z; sv[3] = s0.w;
    sv[4] = s1.x; sv[5] = s1.y; sv[6] = s1.z; sv[7] = s1.w;
#pragma unroll
    for (int i = 0; i < 32; ++i) {
      const int r = w * 64 + i * 2 + half;
      const float* wr_ = wq + (size_t)r * DD + l32 * 8;
      const float4 w0 = *(const float4*)wr_;
      const float4 w1 = *(const float4*)(wr_ + 4);
      float acc = w0.x * sv[0] + w0.y * sv[1] + w0.z * sv[2] + w0.w * sv[3]
                + w1.x * sv[4] + w1.y * sv[5] + w1.z * sv[6] + w1.w * sv[7];
#pragma unroll
      for (int off = 16; off; off >>= 1) acc += __shfl_xor(acc, off);
      if (l32 == 0) qv[r] = acc;
    }
  }
  __syncthreads();

  // ---- qk[h][e] = sum_d qv[h*64+d]*wk[h*64+d][e] * 0.125 ; wave w = head w
  {
    float acc[4] = {};
    for (int d = 0; d < 64; ++d) {
      const int r = w * 64 + d;
      const float qd = qv[r];
      const float4 kv = *(const float4*)(wk + (size_t)r * DD + lane * 4);
      acc[0] += qd * kv.x; acc[1] += qd * kv.y;
      acc[2] += qd * kv.z; acc[3] += qd * kv.w;
    }
#pragma unroll
    for (int i = 0; i < 4; ++i) qk[w][lane * 4 + i] = acc[i] * 0.125f;
  }
  __syncthreads();

  // ---- stream 16 h-rows per wave, accumulate eh/den
  {
    float qkr[NH][4];
#pragma unroll
    for (int h = 0; h < NH; ++h) {
      const float4 qq = *(const float4*)&qk[h][lane * 4];
      qkr[h][0] = qq.x; qkr[h][1] = qq.y; qkr[h][2] = qq.z; qkr[h][3] = qq.w;
    }
    float ehacc[NH][4] = {};
    float dacc[NH] = {};
    const int sbase = chunk * SROWS + w * 16;
    for (int ii = 0; ii < 16; ++ii) {
      const int s = sbase + ii;
      const uint2 hv2 = *(const uint2*)(hbuf + ((size_t)(b * TT + s)) * DD + lane * 4);
      float hv[4];
      hv[0] = bf2f((u16)(hv2.x & 0xffffu)); hv[1] = bf2f((u16)(hv2.x >> 16));
      hv[2] = bf2f((u16)(hv2.y & 0xffffu)); hv[3] = bf2f((u16)(hv2.y >> 16));
      float sc[NH];
#pragma unroll
      for (int h = 0; h < NH; ++h) {
        float p = qkr[h][0] * hv[0] + qkr[h][1] * hv[1]
                + qkr[h][2] * hv[2] + qkr[h][3] * hv[3];
        sc[h] = wred(p);
      }
#pragma unroll
      for (int h = 0; h < NH; ++h) {
        const float E = __expf(fminf(fmaxf(sc[h], -30.f), 30.f));
        dacc[h] += E;
        ehacc[h][0] += E * hv[0]; ehacc[h][1] += E * hv[1];
        ehacc[h][2] += E * hv[2]; ehacc[h][3] += E * hv[3];
      }
    }
#pragma unroll
    for (int h = 0; h < NH; ++h) {
      *(float4*)&ehp[w][h][lane * 4] =
          make_float4(ehacc[h][0], ehacc[h][1], ehacc[h][2], ehacc[h][3]);
      if (lane == 0) denp[w][h] = dacc[h];
    }
  }
  __syncthreads();

  // ---- reduce 4 wave partials, write global
  {
    const size_t pb = ((size_t)(b * SPLIT + chunk)) * NH * DD;
#pragma unroll
    for (int h = 0; h < NH; ++h)
      p_eh[pb + h * DD + tid] =
          ehp[0][h][tid] + ehp[1][h][tid] + ehp[2][h][tid] + ehp[3][h][tid];
    if (tid < NH)
      p_den[(b * SPLIT + chunk) * NH + tid] =
          denp[0][tid] + denp[1][tid] + denp[2][tid] + denp[3][tid];
  }
}

// ---------------------------------------------------------------------------
// Coalesced matvec: 16 waves x 16 rows; 32-lane halves own a row each iter.
// ---------------------------------------------------------------------------
__device__ __forceinline__ void mv256b(const u16* __restrict__ W16,
                                       const float* __restrict__ srcbuf,
                                       float* __restrict__ dst,
                                       int wave, int lane)
{
  const int half = lane >> 5, l32 = lane & 31;
  float s[8];
  {
    const float4 s0 = *(const float4*)(srcbuf + l32 * 8);
    const float4 s1 = *(const float4*)(srcbuf + l32 * 8 + 4);
    s[0] = s0.x; s[1] = s0.y; s[2] = s0.z; s[3] = s0.w;
    s[4] = s1.x; s[5] = s1.y; s[6] = s1.z; s[7] = s1.w;
  }
#pragma unroll
  for (int i = 0; i < 8; ++i) {
    const int r = wave * 16 + i * 2 + half;
    const bf16x8 wv = *(const bf16x8*)(W16 + (size_t)r * DD + l32 * 8);
    float acc = 0.f;
#pragma unroll
    for (int e = 0; e < 8; ++e) acc += bf2f((u16)wv[e]) * s[e];
#pragma unroll
    for (int off = 16; off; off >>= 1) acc += __shfl_xor(acc, off);
    if (l32 == 0) dst[r] = acc;
  }
}

#define LN_STEP(val, gam, bet, dst) \
  __syncthreads(); \
  if (tid < DD) { lnS[tid] = (val); lnQ[tid] = (val) * (val); } \
  __syncthreads(); \
  if (tid < 64) { \
    float s_ = 0.f, q_ = 0.f; \
    _Pragma("unroll") \
    for (int i_ = 0; i_ < 4; ++i_) { s_ += lnS[tid + 64 * i_]; q_ += lnQ[tid + 64 * i_]; } \
    s_ = wred(s_); q_ = wred(q_); \
    if (tid == 0) { const float m_ = s_ * (1.f / DD); red2[0] = m_; red2[1] = rsqrtf(q_ * (1.f / DD) - m_ * m_ + 1e-5f); } \
  } \
  __syncthreads(); \
  if (tid < DD) dst[tid] = ((val) - red2[0]) * red2[1] * gam[tid] + bet[tid]; \
  __syncthreads();

// ---------------------------------------------------------------------------
// tail3: reduce attention partials -> ctx = (eh/den)@wv^T -> out-proj + LN +
// GRN2 + quantile head. grid(BB), 1024 threads.
// wbf: [0]=wo [1]=f1 [2]=f2 [3]=gw [4]=wv
// ---------------------------------------------------------------------------
__global__ __launch_bounds__(1024) void tail3(
    const float* __restrict__ hlast, const float* __restrict__ p_eh,
    const float* __restrict__ p_den, const u16* __restrict__ wbf,
    const float* __restrict__ wob, const float* __restrict__ alng, const float* __restrict__ alnb,
    const float* __restrict__ f1b, const float* __restrict__ f2b,
    const float* __restrict__ gbv, const float* __restrict__ lng, const float* __restrict__ lnb,
    const float* __restrict__ qhw, const float* __restrict__ qhb,
    float* __restrict__ out)
{
  __shared__ float pv[NH * DD];
  __shared__ float den[NH];
  __shared__ float hl[DD], bufA[DD], bufB[DD], bufC[DD], part0[DD];
  __shared__ float lnS[DD], lnQ[DD];
  __shared__ float red2[2];
  const int b = blockIdx.x, tid = threadIdx.x;
  const int wave = tid >> 6, lane = tid & 63;
  const int half = lane >> 5, l32 = lane & 31;

  // reduce partials
  float ehsum = 0.f;
  for (int c = 0; c < SPLIT; ++c)
    ehsum += p_eh[((size_t)(b * SPLIT + c)) * NH * DD + tid];
  if (tid < NH) {
    float s = 0.f;
    for (int c = 0; c < SPLIT; ++c) s += p_den[(b * SPLIT + c) * NH + tid];
    den[tid] = s;
  }
  if (tid < DD) hl[tid] = hlast[(size_t)b * DD + tid];
  __syncthreads();
  pv[tid] = ehsum / den[tid >> 8];
  __syncthreads();

  // ctx[r] = sum_e pv[(r>>6)*256+e] * wv[r][e] -> bufB
  {
    const u16* wv16 = wbf + 4 * 65536;
#pragma unroll
    for (int i = 0; i < 8; ++i) {
      const int r = wave * 16 + i * 2 + half;
      const float* sp = pv + (r >> 6) * DD + l32 * 8;
      const float4 s0 = *(const float4*)sp;
      const float4 s1 = *(const float4*)(sp + 4);
      const bf16x8 wvv = *(const bf16x8*)(wv16 + (size_t)r * DD + l32 * 8);
      float acc = bf2f((u16)wvv[0]) * s0.x + bf2f((u16)wvv[1]) * s0.y
                + bf2f((u16)wvv[2]) * s0.z + bf2f((u16)wvv[3]) * s0.w
                + bf2f((u16)wvv[4]) * s1.x + bf2f((u16)wvv[5]) * s1.y
                + bf2f((u16)wvv[6]) * s1.z + bf2f((u16)wvv[7]) * s1.w;
#pragma unroll
      for (int off = 16; off; off >>= 1) acc += __shfl_xor(acc, off);
      if (l32 == 0) bufB[r] = acc;
    }
  }
  __syncthreads();

  // out proj + residual + LN -> bufA (h2)
  mv256b(wbf + 0 * 65536, bufB, part0, wave, lane);
  __syncthreads();
  float v = 0.f;
  if (tid < DD) v = hl[tid] + part0[tid] + wob[tid];
  LN_STEP(v, alng, alnb, bufA)

  // f1 + ELU -> bufB
  mv256b(wbf + 1 * 65536, bufA, part0, wave, lane);
  __syncthreads();
  if (tid < DD) {
    const float e1 = part0[tid] + f1b[tid];
    bufB[tid] = e1 > 0.f ? e1 : expm1f(e1);
  }
  __syncthreads();

  // f2 -> bufC (eta2)
  mv256b(wbf + 2 * 65536, bufB, part0, wave, lane);
  __syncthreads();
  if (tid < DD) bufC[tid] = part0[tid] + f2b[tid];
  __syncthreads();

  // gate + residual + LN -> bufA (h3)
  mv256b(wbf + 3 * 65536, bufC, part0, wave, lane);
  __syncthreads();
  v = 0.f;
  if (tid < DD) {
    const float g = part0[tid] + gbv[tid];
    v = bufA[tid] + (1.f / (1.f + expf(-g))) * bufC[tid];
  }
  LN_STEP(v, lng, lnb, bufA)

  // quantile head
  if (tid < 64 * NQ) {
    const int qi = tid >> 6, l = tid & 63;
    float acc = 0.f;
#pragma unroll
    for (int i = 0; i < 4; ++i) acc += qhw[(size_t)qi * DD + l + 64 * i] * bufA[l + 64 * i];
    acc = wred(acc);
    if (l == 0) out[b * NQ + qi] = acc + qhb[qi];
  }
}

// ---------------------------------------------------------------------------
extern "C" void kernel_launch(void* const* d_in, const int* in_sizes, int n_in,
                              void* d_out, int out_size, void* d_ws, size_t ws_size,
                              hipStream_t stream)
{
  const float* x       = (const float*)d_in[0];
  const float* g1_f1w  = (const float*)d_in[1];
  const float* g1_f1b  = (const float*)d_in[2];
  const float* g1_f2w  = (const float*)d_in[3];
  const float* g1_f2b  = (const float*)d_in[4];
  const float* g1_gw   = (const float*)d_in[5];
  const float* g1_gb   = (const float*)d_in[6];
  const float* g1_lng  = (const float*)d_in[7];
  const float* g1_lnb  = (const float*)d_in[8];
  const float* wq      = (const float*)d_in[9];
  const float* wk      = (const float*)d_in[10];
  const float* wv      = (const float*)d_in[11];
  const float* wo_w    = (const float*)d_in[12];
  const float* wo_b    = (const float*)d_in[13];
  const float* attn_lng= (const float*)d_in[14];
  const float* attn_lnb= (const float*)d_in[15];
  const float* g2_f1w  = (const float*)d_in[16];
  const float* g2_f1b  = (const float*)d_in[17];
  const float* g2_f2w  = (const float*)d_in[18];
  const float* g2_f2b  = (const float*)d_in[19];
  const float* g2_gw   = (const float*)d_in[20];
  const float* g2_gb   = (const float*)d_in[21];
  const float* g2_lng  = (const float*)d_in[22];
  const float* g2_lnb  = (const float*)d_in[23];
  const float* qh_w    = (const float*)d_in[24];
  const float* qh_b    = (const float*)d_in[25];
  float* out = (float*)d_out;

  char* w8 = (char*)d_ws;
  u16*  wbf   = (u16*)(w8);                           // 5*128KB bf16 tail weights
  float* p_eh  = (float*)(w8 + ((size_t)1 << 20));    // 512 KB
  float* p_den = (float*)(w8 + ((size_t)1600 << 10)); // 2 KB
  u16*  eta1  = (u16*)(w8 + ((size_t)2  << 20));      // 4 MB
  u16*  eta2  = (u16*)(w8 + ((size_t)6  << 20));      // 4 MB
  u16*  hbuf  = (u16*)(w8 + ((size_t)10 << 20));      // 4 MB
  float* hlast = (float*)(w8 + ((size_t)14 << 20));   // 8 KB

  const dim3 blk(256);
  const dim3 g1(MM / 64, DD / 64);

  gemm64<false, 1><<<g1, blk, 0, stream>>>((const void*)x,    g1_f1w, g1_f1b, eta1);
  gemm64<true,  0><<<g1, blk, 0, stream>>>((const void*)eta1, g1_f2w, g1_f2b, eta2);
  grn_gate_ln<<<dim3(MM / 32), blk, 0, stream>>>(eta2, g1_gw, g1_gb, x, g1_lng, g1_lnb, hbuf, hlast);
  attn_partial<<<dim3(SPLIT, BB), blk, 0, stream>>>(hlast, hbuf, wq, wk,
                                                    wo_w, g2_f1w, g2_f2w, g2_gw, wv,
                                                    wbf, p_eh, p_den);
  tail3<<<dim3(BB), dim3(1024), 0, stream>>>(hlast, p_eh, p_den, wbf,
                                             wo_b, attn_lng, attn_lnb,
                                             g2_f1b, g2_f2b, g2_gb, g2_lng, g2_lnb,
                                             qh_w, qh_b, out);
}

// Round 8
// 82.018 us; speedup vs baseline: 1.4169x; 1.0925x over previous
//
#include <hip/hip_runtime.h>
#include <hip/hip_bf16.h>
#include <math.h>

#define DD 256
#define BB 8
#define TT 1024
#define MM (BB*TT)
#define NH 4
#define DKH 64
#define NQ 3
#define SPLIT 32
#define SROWS (TT/SPLIT)   // 32

typedef __attribute__((ext_vector_type(8))) short bf16x8;
typedef __attribute__((ext_vector_type(4))) float f32x4;
typedef unsigned short u16;
typedef unsigned int u32;

__device__ __forceinline__ float bf2f(u16 u) {
  return __uint_as_float(((u32)u) << 16);
}
__device__ __forceinline__ u16 f2bf(float x) {
  __hip_bfloat16 h = __float2bfloat16(x);
  return *reinterpret_cast<u16*>(&h);
}
__device__ __forceinline__ uint2 pack4(float a, float b, float c, float d) {
  uint2 r;
  r.x = (u32)f2bf(a) | ((u32)f2bf(b) << 16);
  r.y = (u32)f2bf(c) | ((u32)f2bf(d) << 16);
  return r;
}
__device__ __forceinline__ float wred(float v) {
#pragma unroll
  for (int off = 32; off; off >>= 1) v += __shfl_xor(v, off);
  return v;
}

// ---------------------------------------------------------------------------
// Single-stage GEMM: out[M,256] = act(A[M,256] @ W[256,256]^T + bias).
// ---------------------------------------------------------------------------
template<bool ABF, int ACT>   // ACT: 0 = none, 1 = ELU
__global__ __launch_bounds__(256) void gemm64(const void* __restrict__ A_,
                                              const float* __restrict__ W,
                                              const float* __restrict__ bias,
                                              u16* __restrict__ out)
{
  __shared__ u16 As[64][264];
  __shared__ u16 Bs[64][264];
  const int tid  = threadIdx.x;
  const int lane = tid & 63, wave = tid >> 6;
  const int wr = wave >> 1, wc = wave & 1;
  const int q  = lane >> 4, lr = lane & 15;
  const int m0 = blockIdx.x * 64, n0 = blockIdx.y * 64;

#pragma unroll
  for (int p = 0; p < 8; ++p) {
    const int c = tid + p * 256;
    const int row = c >> 5, col = (c & 31) * 8;
    if constexpr (ABF) {
      *(uint4*)&As[row][col] = *(const uint4*)((const u16*)A_ + (size_t)(m0 + row) * DD + col);
    } else {
      const float* ap = (const float*)A_ + (size_t)(m0 + row) * DD + col;
      const float4 v0 = *(const float4*)ap, v1 = *(const float4*)(ap + 4);
      *(uint2*)&As[row][col]     = pack4(v0.x, v0.y, v0.z, v0.w);
      *(uint2*)&As[row][col + 4] = pack4(v1.x, v1.y, v1.z, v1.w);
    }
    const float* wp = W + (size_t)(n0 + row) * DD + col;
    const float4 w0 = *(const float4*)wp, w1 = *(const float4*)(wp + 4);
    *(uint2*)&Bs[row][col]     = pack4(w0.x, w0.y, w0.z, w0.w);
    *(uint2*)&Bs[row][col + 4] = pack4(w1.x, w1.y, w1.z, w1.w);
  }
  __syncthreads();

  f32x4 acc[2][2] = {};
#pragma unroll
  for (int kk = 0; kk < 8; ++kk) {
    const int koff = kk * 32 + q * 8;
    bf16x8 av[2], bv[2];
    av[0] = *(const bf16x8*)&As[wr * 32 + lr][koff];
    av[1] = *(const bf16x8*)&As[wr * 32 + 16 + lr][koff];
    bv[0] = *(const bf16x8*)&Bs[wc * 32 + lr][koff];
    bv[1] = *(const bf16x8*)&Bs[wc * 32 + 16 + lr][koff];
#pragma unroll
    for (int i = 0; i < 2; ++i)
#pragma unroll
      for (int j = 0; j < 2; ++j)
        acc[i][j] = __builtin_amdgcn_mfma_f32_16x16x32_bf16(av[i], bv[j], acc[i][j], 0, 0, 0);
  }

#pragma unroll
  for (int i = 0; i < 2; ++i) {
#pragma unroll
    for (int j = 0; j < 2; ++j) {
      const int col = n0 + wc * 32 + j * 16 + lr;
      const float bvv = bias ? bias[col] : 0.f;
#pragma unroll
      for (int t = 0; t < 4; ++t) {
        const int row = m0 + wr * 32 + i * 16 + q * 4 + t;
        float v = acc[i][j][t] + bvv;
        if (ACT == 1) v = v > 0.f ? v : expm1f(v);
        out[(size_t)row * DD + col] = f2bf(v);
      }
    }
  }
}

// ---------------------------------------------------------------------------
// K3: gate = eta2 @ gw^T + gb; h = LN(x + sigmoid(gate)*eta2) fused.
// ---------------------------------------------------------------------------
__global__ __launch_bounds__(256) void grn_gate_ln(
    const u16* __restrict__ eta2, const float* __restrict__ W,
    const float* __restrict__ gb, const float* __restrict__ x,
    const float* __restrict__ lng, const float* __restrict__ lnb,
    u16* __restrict__ hout, float* __restrict__ hlast)
{
  __shared__ u16 As[32][136];
  __shared__ u16 Bs[256][136];
  __shared__ float red_s[32][5];
  __shared__ float red_q[32][5];
  __shared__ float smean[32], srstd[32];

  const int tid  = threadIdx.x;
  const int lane = tid & 63, wave = tid >> 6;
  const int q  = lane >> 4, lr = lane & 15;
  const int m0 = blockIdx.x * 32;

  f32x4 acc[2][4] = {};

  for (int k0 = 0; k0 < DD; k0 += 128) {
#pragma unroll
    for (int p = 0; p < 2; ++p) {
      const int c = tid + p * 256;
      const int row = c >> 4, col = (c & 15) * 8;
      *(uint4*)&As[row][col] = *(const uint4*)(eta2 + (size_t)(m0 + row) * DD + k0 + col);
    }
#pragma unroll
    for (int p = 0; p < 16; ++p) {
      const int c = tid + p * 256;
      const int row = c >> 4, col = (c & 15) * 8;
      const float* wp = W + (size_t)row * DD + k0 + col;
      const float4 w0 = *(const float4*)wp, w1 = *(const float4*)(wp + 4);
      *(uint2*)&Bs[row][col]     = pack4(w0.x, w0.y, w0.z, w0.w);
      *(uint2*)&Bs[row][col + 4] = pack4(w1.x, w1.y, w1.z, w1.w);
    }
    __syncthreads();
#pragma unroll
    for (int kk = 0; kk < 4; ++kk) {
      const int koff = kk * 32 + q * 8;
      bf16x8 av[2], bv[4];
#pragma unroll
      for (int i = 0; i < 2; ++i) av[i] = *(const bf16x8*)&As[i * 16 + lr][koff];
#pragma unroll
      for (int j = 0; j < 4; ++j) bv[j] = *(const bf16x8*)&Bs[wave * 64 + j * 16 + lr][koff];
#pragma unroll
      for (int i = 0; i < 2; ++i)
#pragma unroll
        for (int j = 0; j < 4; ++j)
          acc[i][j] = __builtin_amdgcn_mfma_f32_16x16x32_bf16(av[i], bv[j], acc[i][j], 0, 0, 0);
    }
    __syncthreads();
  }

  float pre[2][4][4];
#pragma unroll
  for (int i = 0; i < 2; ++i) {
#pragma unroll
    for (int j = 0; j < 4; ++j) {
      const int n = wave * 64 + j * 16 + lr;
      const float gbn = gb[n];
#pragma unroll
      for (int t = 0; t < 4; ++t) {
        const int grow = m0 + i * 16 + q * 4 + t;
        const float gate = acc[i][j][t] + gbn;
        const float sig = 1.f / (1.f + expf(-gate));
        const float e2 = bf2f(eta2[(size_t)grow * DD + n]);
        pre[i][j][t] = x[(size_t)grow * DD + n] + sig * e2;
      }
    }
  }
#pragma unroll
  for (int i = 0; i < 2; ++i) {
#pragma unroll
    for (int t = 0; t < 4; ++t) {
      float s = 0.f, sq = 0.f;
#pragma unroll
      for (int j = 0; j < 4; ++j) { const float v = pre[i][j][t]; s += v; sq += v * v; }
#pragma unroll
      for (int m = 1; m <= 8; m <<= 1) { s += __shfl_xor(s, m); sq += __shfl_xor(sq, m); }
      if (lr == 0) {
        const int ml = i * 16 + q * 4 + t;
        red_s[ml][wave] = s;
        red_q[ml][wave] = sq;
      }
    }
  }
  __syncthreads();
  if (tid < 32) {
    const float s  = red_s[tid][0] + red_s[tid][1] + red_s[tid][2] + red_s[tid][3];
    const float sq = red_q[tid][0] + red_q[tid][1] + red_q[tid][2] + red_q[tid][3];
    const float mean = s * (1.f / DD);
    const float var = sq * (1.f / DD) - mean * mean;
    smean[tid] = mean;
    srstd[tid] = rsqrtf(var + 1e-5f);
  }
  __syncthreads();
#pragma unroll
  for (int i = 0; i < 2; ++i) {
#pragma unroll
    for (int j = 0; j < 4; ++j) {
      const int n = wave * 64 + j * 16 + lr;
      const float gn = lng[n], bn = lnb[n];
#pragma unroll
      for (int t = 0; t < 4; ++t) {
        const int ml = i * 16 + q * 4 + t;
        const int grow = m0 + ml;
        const float hn = (pre[i][j][t] - smean[ml]) * srstd[ml] * gn + bn;
        hout[(size_t)grow * DD + n] = f2bf(hn);
        if ((grow & (TT - 1)) == (TT - 1))
          hlast[(size_t)(grow >> 10) * DD + n] = hn;
      }
    }
  }
}

// ---------------------------------------------------------------------------
// attn2: K/V-free attention, latency-lean. grid (SPLIT, BB), 256 threads.
// Redundant per-block q/qk compute (cheap, parallel); 32-row h-chunk staged
// in LDS; scores via 8-thread/row 3-level shfl; eh via thread-per-column.
// Also casts the 5 tail weight matrices to bf16 (wo,f1,f2,gw,wv).
// ---------------------------------------------------------------------------
__global__ __launch_bounds__(256) void attn2(
    const float* __restrict__ hlast, const u16* __restrict__ hbuf,
    const float* __restrict__ wq, const float* __restrict__ wk,
    const float* __restrict__ wo_w, const float* __restrict__ f1w,
    const float* __restrict__ f2w, const float* __restrict__ gw,
    const float* __restrict__ wv,
    u16* __restrict__ wbf,
    float* __restrict__ p_eh,   // [BB][SPLIT][NH][DD]
    float* __restrict__ p_den)  // [BB][SPLIT][NH]
{
  __shared__ float hl[DD];
  __shared__ float qv[DD];
  __shared__ float qk4[NH][DD];
  __shared__ u16 hch[SROWS][264];
  __shared__ float E[SROWS][NH];
  const int chunk = blockIdx.x, b = blockIdx.y;
  const int tid = threadIdx.x;

  // ---- tail-weight cast: 5*65536 / 256 blocks = 1280 elems = 5/thread
  {
    const int bid = b * SPLIT + chunk;
    const int base = bid * 1280;
#pragma unroll
    for (int r = 0; r < 5; ++r) {
      const int e = base + r * 256 + tid;
      const int mi = e >> 16, off = e & 65535;
      const float* s = (mi == 0) ? wo_w : (mi == 1) ? f1w : (mi == 2) ? f2w
                     : (mi == 3) ? gw : wv;
      wbf[e] = f2bf(s[off]);
    }
  }

  // ---- stage h-chunk (32 rows) + hlast
  hl[tid] = hlast[(size_t)b * DD + tid];
#pragma unroll
  for (int p = 0; p < 4; ++p) {
    const int idx = p * 256 + tid;
    const int row = idx >> 5, col = (idx & 31) * 8;
    *(uint4*)&hch[row][col] =
        *(const uint4*)(hbuf + ((size_t)(b * TT + chunk * SROWS + row)) * DD + col);
  }
  __syncthreads();

  // ---- q[r] = hl . wq[r], 4 threads/row (2-level shfl)
  {
    const int j = tid >> 2, seg = tid & 3;
    const float* sp = hl + seg * 64;
#pragma unroll
    for (int pass = 0; pass < 4; ++pass) {
      const int r = pass * 64 + j;
      const float* wr_ = wq + (size_t)r * DD + seg * 64;
      float acc = 0.f;
#pragma unroll
      for (int k = 0; k < 64; k += 4) {
        const float4 w4 = *(const float4*)(wr_ + k);
        acc += w4.x * sp[k] + w4.y * sp[k + 1] + w4.z * sp[k + 2] + w4.w * sp[k + 3];
      }
      acc += __shfl_xor(acc, 1);
      acc += __shfl_xor(acc, 2);
      if (seg == 0) qv[r] = acc;
    }
  }
  __syncthreads();

  // ---- qk[h][e] = 0.125 * sum_d qv[h*64+d] * wk[h*64+d][e]; e = tid
  {
#pragma unroll
    for (int h = 0; h < NH; ++h) {
      float acc = 0.f;
      const float* wkb = wk + (size_t)(h * DKH) * DD + tid;
#pragma unroll 8
      for (int d = 0; d < DKH; ++d)
        acc += qv[h * DKH + d] * wkb[(size_t)d * DD];
      qk4[h][tid] = acc * 0.125f;
    }
  }
  __syncthreads();

  // ---- scores: s = tid>>3, 8 threads/row each covering 32 d's
  {
    const int s = tid >> 3, sub = tid & 7;
    const u16* hp = &hch[s][sub * 32];
    float part[NH] = {};
#pragma unroll
    for (int v = 0; v < 4; ++v) {
      const bf16x8 h8 = *(const bf16x8*)(hp + v * 8);
      float hf[8];
#pragma unroll
      for (int e = 0; e < 8; ++e) hf[e] = bf2f((u16)h8[e]);
#pragma unroll
      for (int h = 0; h < NH; ++h) {
        const float* qp = &qk4[h][sub * 32 + v * 8];
#pragma unroll
        for (int e = 0; e < 8; ++e) part[h] += hf[e] * qp[e];
      }
    }
#pragma unroll
    for (int h = 0; h < NH; ++h) {
      float p = part[h];
      p += __shfl_xor(p, 1);
      p += __shfl_xor(p, 2);
      p += __shfl_xor(p, 4);
      if (sub == 0) E[s][h] = __expf(fminf(fmaxf(p, -30.f), 30.f));
    }
  }
  __syncthreads();

  // ---- eh[c] per head: thread owns column c = tid
  {
    float eh[NH] = {};
    for (int s = 0; s < SROWS; ++s) {
      const float hv = bf2f(hch[s][tid]);
      const float4 E4 = *(const float4*)&E[s][0];
      eh[0] += E4.x * hv; eh[1] += E4.y * hv;
      eh[2] += E4.z * hv; eh[3] += E4.w * hv;
    }
    const size_t pb = ((size_t)(b * SPLIT + chunk)) * NH * DD;
#pragma unroll
    for (int h = 0; h < NH; ++h) p_eh[pb + h * DD + tid] = eh[h];
  }
  if (tid < NH) {
    float s = 0.f;
    for (int s2 = 0; s2 < SROWS; ++s2) s += E[s2][tid];
    p_den[(b * SPLIT + chunk) * NH + tid] = s;
  }
}

// ---------------------------------------------------------------------------
// Coalesced matvec: 16 waves x 16 rows; 32-lane halves own a row each iter.
// ---------------------------------------------------------------------------
__device__ __forceinline__ void mv256b(const u16* __restrict__ W16,
                                       const float* __restrict__ srcbuf,
                                       float* __restrict__ dst,
                                       int wave, int lane)
{
  const int half = lane >> 5, l32 = lane & 31;
  float s[8];
  {
    const float4 s0 = *(const float4*)(srcbuf + l32 * 8);
    const float4 s1 = *(const float4*)(srcbuf + l32 * 8 + 4);
    s[0] = s0.x; s[1] = s0.y; s[2] = s0.z; s[3] = s0.w;
    s[4] = s1.x; s[5] = s1.y; s[6] = s1.z; s[7] = s1.w;
  }
#pragma unroll
  for (int i = 0; i < 8; ++i) {
    const int r = wave * 16 + i * 2 + half;
    const bf16x8 wv = *(const bf16x8*)(W16 + (size_t)r * DD + l32 * 8);
    float acc = 0.f;
#pragma unroll
    for (int e = 0; e < 8; ++e) acc += bf2f((u16)wv[e]) * s[e];
#pragma unroll
    for (int off = 16; off; off >>= 1) acc += __shfl_xor(acc, off);
    if (l32 == 0) dst[r] = acc;
  }
}

#define LN_STEP(val, gam, bet, dst) \
  __syncthreads(); \
  if (tid < DD) { lnS[tid] = (val); lnQ[tid] = (val) * (val); } \
  __syncthreads(); \
  if (tid < 64) { \
    float s_ = 0.f, q_ = 0.f; \
    _Pragma("unroll") \
    for (int i_ = 0; i_ < 4; ++i_) { s_ += lnS[tid + 64 * i_]; q_ += lnQ[tid + 64 * i_]; } \
    s_ = wred(s_); q_ = wred(q_); \
    if (tid == 0) { const float m_ = s_ * (1.f / DD); red2[0] = m_; red2[1] = rsqrtf(q_ * (1.f / DD) - m_ * m_ + 1e-5f); } \
  } \
  __syncthreads(); \
  if (tid < DD) dst[tid] = ((val) - red2[0]) * red2[1] * gam[tid] + bet[tid]; \
  __syncthreads();

// ---------------------------------------------------------------------------
// tail3: reduce attention partials -> ctx = (eh/den)@wv^T -> out-proj + LN +
// GRN2 + quantile head. grid(BB), 1024 threads.
// wbf: [0]=wo [1]=f1 [2]=f2 [3]=gw [4]=wv
// ---------------------------------------------------------------------------
__global__ __launch_bounds__(1024) void tail3(
    const float* __restrict__ hlast, const float* __restrict__ p_eh,
    const float* __restrict__ p_den, const u16* __restrict__ wbf,
    const float* __restrict__ wob, const float* __restrict__ alng, const float* __restrict__ alnb,
    const float* __restrict__ f1b, const float* __restrict__ f2b,
    const float* __restrict__ gbv, const float* __restrict__ lng, const float* __restrict__ lnb,
    const float* __restrict__ qhw, const float* __restrict__ qhb,
    float* __restrict__ out)
{
  __shared__ float pv[NH * DD];
  __shared__ float den[NH];
  __shared__ float hl[DD], bufA[DD], bufB[DD], bufC[DD], part0[DD];
  __shared__ float lnS[DD], lnQ[DD];
  __shared__ float red2[2];
  const int b = blockIdx.x, tid = threadIdx.x;
  const int wave = tid >> 6, lane = tid & 63;
  const int half = lane >> 5, l32 = lane & 31;

  // reduce partials
  float ehsum = 0.f;
  for (int c = 0; c < SPLIT; ++c)
    ehsum += p_eh[((size_t)(b * SPLIT + c)) * NH * DD + tid];
  if (tid < NH) {
    float s = 0.f;
    for (int c = 0; c < SPLIT; ++c) s += p_den[(b * SPLIT + c) * NH + tid];
    den[tid] = s;
  }
  if (tid < DD) hl[tid] = hlast[(size_t)b * DD + tid];
  __syncthreads();
  pv[tid] = ehsum / den[tid >> 8];
  __syncthreads();

  // ctx[r] = sum_e pv[(r>>6)*256+e] * wv[r][e] -> bufB
  {
    const u16* wv16 = wbf + 4 * 65536;
#pragma unroll
    for (int i = 0; i < 8; ++i) {
      const int r = wave * 16 + i * 2 + half;
      const float* sp = pv + (r >> 6) * DD + l32 * 8;
      const float4 s0 = *(const float4*)sp;
      const float4 s1 = *(const float4*)(sp + 4);
      const bf16x8 wvv = *(const bf16x8*)(wv16 + (size_t)r * DD + l32 * 8);
      float acc = bf2f((u16)wvv[0]) * s0.x + bf2f((u16)wvv[1]) * s0.y
                + bf2f((u16)wvv[2]) * s0.z + bf2f((u16)wvv[3]) * s0.w
                + bf2f((u16)wvv[4]) * s1.x + bf2f((u16)wvv[5]) * s1.y
                + bf2f((u16)wvv[6]) * s1.z + bf2f((u16)wvv[7]) * s1.w;
#pragma unroll
      for (int off = 16; off; off >>= 1) acc += __shfl_xor(acc, off);
      if (l32 == 0) bufB[r] = acc;
    }
  }
  __syncthreads();

  // out proj + residual + LN -> bufA (h2)
  mv256b(wbf + 0 * 65536, bufB, part0, wave, lane);
  __syncthreads();
  float v = 0.f;
  if (tid < DD) v = hl[tid] + part0[tid] + wob[tid];
  LN_STEP(v, alng, alnb, bufA)

  // f1 + ELU -> bufB
  mv256b(wbf + 1 * 65536, bufA, part0, wave, lane);
  __syncthreads();
  if (tid < DD) {
    const float e1 = part0[tid] + f1b[tid];
    bufB[tid] = e1 > 0.f ? e1 : expm1f(e1);
  }
  __syncthreads();

  // f2 -> bufC (eta2)
  mv256b(wbf + 2 * 65536, bufB, part0, wave, lane);
  __syncthreads();
  if (tid < DD) bufC[tid] = part0[tid] + f2b[tid];
  __syncthreads();

  // gate + residual + LN -> bufA (h3)
  mv256b(wbf + 3 * 65536, bufC, part0, wave, lane);
  __syncthreads();
  v = 0.f;
  if (tid < DD) {
    const float g = part0[tid] + gbv[tid];
    v = bufA[tid] + (1.f / (1.f + expf(-g))) * bufC[tid];
  }
  LN_STEP(v, lng, lnb, bufA)

  // quantile head
  if (tid < 64 * NQ) {
    const int qi = tid >> 6, l = tid & 63;
    float acc = 0.f;
#pragma unroll
    for (int i = 0; i < 4; ++i) acc += qhw[(size_t)qi * DD + l + 64 * i] * bufA[l + 64 * i];
    acc = wred(acc);
    if (l == 0) out[b * NQ + qi] = acc + qhb[qi];
  }
}

// ---------------------------------------------------------------------------
extern "C" void kernel_launch(void* const* d_in, const int* in_sizes, int n_in,
                              void* d_out, int out_size, void* d_ws, size_t ws_size,
                              hipStream_t stream)
{
  const float* x       = (const float*)d_in[0];
  const float* g1_f1w  = (const float*)d_in[1];
  const float* g1_f1b  = (const float*)d_in[2];
  const float* g1_f2w  = (const float*)d_in[3];
  const float* g1_f2b  = (const float*)d_in[4];
  const float* g1_gw   = (const float*)d_in[5];
  const float* g1_gb   = (const float*)d_in[6];
  const float* g1_lng  = (const float*)d_in[7];
  const float* g1_lnb  = (const float*)d_in[8];
  const float* wq      = (const float*)d_in[9];
  const float* wk      = (const float*)d_in[10];
  const float* wv      = (const float*)d_in[11];
  const float* wo_w    = (const float*)d_in[12];
  const float* wo_b    = (const float*)d_in[13];
  const float* attn_lng= (const float*)d_in[14];
  const float* attn_lnb= (const float*)d_in[15];
  const float* g2_f1w  = (const float*)d_in[16];
  const float* g2_f1b  = (const float*)d_in[17];
  const float* g2_f2w  = (const float*)d_in[18];
  const float* g2_f2b  = (const float*)d_in[19];
  const float* g2_gw   = (const float*)d_in[20];
  const float* g2_gb   = (const float*)d_in[21];
  const float* g2_lng  = (const float*)d_in[22];
  const float* g2_lnb  = (const float*)d_in[23];
  const float* qh_w    = (const float*)d_in[24];
  const float* qh_b    = (const float*)d_in[25];
  float* out = (float*)d_out;

  char* w8 = (char*)d_ws;
  u16*  wbf   = (u16*)(w8);                           // 5*128KB bf16 tail weights
  float* p_eh  = (float*)(w8 + ((size_t)1 << 20));    // 1 MB
  float* p_den = (float*)(w8 + ((size_t)2100 << 10)); // 4 KB
  u16*  eta1  = (u16*)(w8 + ((size_t)4  << 20));      // 4 MB
  u16*  eta2  = (u16*)(w8 + ((size_t)8  << 20));      // 4 MB
  u16*  hbuf  = (u16*)(w8 + ((size_t)12 << 20));      // 4 MB
  float* hlast = (float*)(w8 + ((size_t)16 << 20));   // 8 KB

  const dim3 blk(256);
  const dim3 g1(MM / 64, DD / 64);

  gemm64<false, 1><<<g1, blk, 0, stream>>>((const void*)x,    g1_f1w, g1_f1b, eta1);
  gemm64<true,  0><<<g1, blk, 0, stream>>>((const void*)eta1, g1_f2w, g1_f2b, eta2);
  grn_gate_ln<<<dim3(MM / 32), blk, 0, stream>>>(eta2, g1_gw, g1_gb, x, g1_lng, g1_lnb, hbuf, hlast);
  attn2<<<dim3(SPLIT, BB), blk, 0, stream>>>(hlast, hbuf, wq, wk,
                                             wo_w, g2_f1w, g2_f2w, g2_gw, wv,
                                             wbf, p_eh, p_den);
  tail3<<<dim3(BB), dim3(1024), 0, stream>>>(hlast, p_eh, p_den, wbf,
                                             wo_b, attn_lng, attn_lnb,
                                             g2_f1b, g2_f2b, g2_gb, g2_lng, g2_lnb,
                                             qh_w, qh_b, out);
}